// Round 4
// baseline (1264.122 us; speedup 1.0000x reference)
//
#include <hip/hip_runtime.h>
#include <hip/hip_bf16.h>
#include <cstdint>
#include <cstddef>

typedef __bf16 bf16x8 __attribute__((ext_vector_type(8)));
typedef float f32x4 __attribute__((ext_vector_type(4)));
using bf16_t = __hip_bfloat16;

constexpr int kHID = 1536;
constexpr int kH = 8;
constexpr int kD = 192;
constexpr int kW = 12;
constexpr int kC = 24;
constexpr int kF = 13;
constexpr int kB = 4;
constexpr int kT = 4096;
constexpr int kU = 342;        // ceil(T/W)
constexpr int kNQKV = 4608;    // 3*HID
constexpr int kM = kB * kT;    // 16384
constexpr int kKV = 2 * kHID;  // 3072

// ws layout (bytes): [kv bf16][wt bf16][sinb f32]
constexpr size_t kKvBytes = (size_t)kM * kKV * 2;      // 100,663,296
constexpr size_t kWtBytes = (size_t)kNQKV * kHID * 2;  // 14,155,776
constexpr size_t kSinBytes = (size_t)kF * kHID * 4;    // 79,872
constexpr size_t kWtOff = kKvBytes;
constexpr size_t kSinOff = kWtOff + kWtBytes;
constexpr size_t kWsNeed = kSinOff + kSinBytes;

// ---------------------------------------------------------------------------
// Kernel 1: transpose + concat weights (fp32 in) -> wt[n][k] (bf16)
// n in [0,4608): [wq|wk|wv]^T
// ---------------------------------------------------------------------------
__global__ __launch_bounds__(256) void transpose_w(const float* __restrict__ wq,
                                                   const float* __restrict__ wk,
                                                   const float* __restrict__ wv,
                                                   bf16_t* __restrict__ wt) {
  __shared__ bf16_t tile[32][33];
  const int s = blockIdx.z;
  const float* w = (s == 0) ? wq : (s == 1) ? wk : wv;
  const int k0 = blockIdx.x * 32, n0 = blockIdx.y * 32;
  for (int i = threadIdx.y; i < 32; i += 8)
    tile[i][threadIdx.x] = (bf16_t)w[(size_t)(k0 + i) * kHID + n0 + threadIdx.x];
  __syncthreads();
  for (int i = threadIdx.y; i < 32; i += 8)
    wt[(size_t)(s * kHID + n0 + i) * kHID + k0 + threadIdx.x] = tile[threadIdx.x][i];
}

// ---------------------------------------------------------------------------
// Kernel 2: sin_emb[f][n] = timing_signal(pos)[f] @ w_pos  (fp32 in/out)
// ---------------------------------------------------------------------------
__global__ __launch_bounds__(256) void sinemb_kernel(const float* __restrict__ w_pos,
                                                     float* __restrict__ sinb) {
  __shared__ float ts[kHID];
  const int f = blockIdx.y;
  const int n = blockIdx.x * 256 + threadIdx.x;
  const float pos = (float)(12 - f);  // pos[f] = MAX_PAST - f, MAX_FUT = 0
  const float log_inc = logf(10000.0f) / 767.0f;
  for (int j = threadIdx.x; j < 768; j += 256) {
    float inv = expf(-(float)j * log_inc);
    float a = pos * inv;
    ts[j] = sinf(a);
    ts[768 + j] = cosf(a);
  }
  __syncthreads();
  float acc = 0.0f;
  for (int m = 0; m < kHID; m++) acc += ts[m] * w_pos[(size_t)m * kHID + n];
  sinb[f * kHID + n] = acc;
}

// ---------------------------------------------------------------------------
// Kernel 3: QKV GEMM. [M=16384][N=4608] = hs[M][1536](fp32->bf16) @ wt[N][1536]^T
// q-cols (n<1536) -> d_out (fp32, same layout as final output);
// k/v-cols -> kv ws buffer (bf16).
// ---------------------------------------------------------------------------
__global__ __launch_bounds__(256) void gemm_qkv(const float* __restrict__ hs,
                                                const bf16_t* __restrict__ wt,
                                                float* __restrict__ qout,
                                                bf16_t* __restrict__ kvout) {
  __shared__ bf16_t As[128 * 32];
  __shared__ bf16_t Bs[128 * 32];
  const int tid = threadIdx.x;
  const int lane = tid & 63, wid = tid >> 6;
  const int t0 = blockIdx.y * 128, n0 = blockIdx.x * 128;
  const int mb = lane & 15, quad = lane >> 4;
  const int wrow = (wid >> 1) * 64, wcol = (wid & 1) * 64;

  f32x4 acc[4][4] = {};

  // chunk c (0..511): row c>>2, k-offset (c&3)*8; LDS elem offset c*8
  const int c0 = tid, c1 = tid + 256;
  const float* a0 = hs + (size_t)(t0 + (c0 >> 2)) * kHID + (c0 & 3) * 8;
  const float* a1 = hs + (size_t)(t0 + (c1 >> 2)) * kHID + (c1 & 3) * 8;
  const bf16_t* b0 = wt + (size_t)(n0 + (c0 >> 2)) * kHID + (c0 & 3) * 8;
  const bf16_t* b1 = wt + (size_t)(n0 + (c1 >> 2)) * kHID + (c1 & 3) * 8;

  for (int k0 = 0; k0 < kHID; k0 += 32) {
    f32x4 p0 = *(const f32x4*)a0, p1 = *(const f32x4*)(a0 + 4);
    f32x4 p2 = *(const f32x4*)a1, p3 = *(const f32x4*)(a1 + 4);
    bf16x8 bv0 = *(const bf16x8*)b0;
    bf16x8 bv1 = *(const bf16x8*)b1;
    a0 += 32; a1 += 32; b0 += 32; b1 += 32;
    bf16x8 av0, av1;
#pragma unroll
    for (int e = 0; e < 4; e++) {
      av0[e] = (__bf16)p0[e]; av0[e + 4] = (__bf16)p1[e];
      av1[e] = (__bf16)p2[e]; av1[e + 4] = (__bf16)p3[e];
    }

    __syncthreads();
    *(bf16x8*)(&As[c0 * 8]) = av0;
    *(bf16x8*)(&As[c1 * 8]) = av1;
    *(bf16x8*)(&Bs[c0 * 8]) = bv0;
    *(bf16x8*)(&Bs[c1 * 8]) = bv1;
    __syncthreads();

    bf16x8 af[4], bg[4];
#pragma unroll
    for (int i = 0; i < 4; i++)
      af[i] = *(const bf16x8*)(&As[(wrow + i * 16 + mb) * 32 + quad * 8]);
#pragma unroll
    for (int j = 0; j < 4; j++)
      bg[j] = *(const bf16x8*)(&Bs[(wcol + j * 16 + mb) * 32 + quad * 8]);
#pragma unroll
    for (int i = 0; i < 4; i++)
#pragma unroll
      for (int j = 0; j < 4; j++)
        acc[i][j] = __builtin_amdgcn_mfma_f32_16x16x32_bf16(af[i], bg[j], acc[i][j], 0, 0, 0);
  }

  // epilogue: C/D layout col=lane&15 (N side), row=quad*4+reg (M side)
  const bool isq = (n0 < kHID);  // block-uniform
#pragma unroll
  for (int i = 0; i < 4; i++)
#pragma unroll
    for (int j = 0; j < 4; j++)
#pragma unroll
      for (int r = 0; r < 4; r++) {
        int row = t0 + wrow + i * 16 + quad * 4 + r;
        int col = wcol + j * 16 + mb;
        if (isq) {
          qout[(size_t)row * kHID + n0 + col] = acc[i][j][r];
        } else {
          kvout[(size_t)row * kKV + (n0 - kHID) + col] = (bf16_t)acc[i][j][r];
        }
      }
}

// ---------------------------------------------------------------------------
// Kernel 4: local relative attention. grid (U, B, H), block 256.
// tb[w][c] = term_bd[w][c-w] valid iff 0 <= c-w <= 12 (== causal band mask).
// Q read fp32 from d_out; ctx overwrites the same rows (no cross-block hazard).
// ---------------------------------------------------------------------------
__global__ __launch_bounds__(256) void attn_kernel(const bf16_t* __restrict__ kv,
                                                   const unsigned char* __restrict__ mask,
                                                   const float* __restrict__ sinb,
                                                   const float* __restrict__ pds,
                                                   float* __restrict__ out) {
  const int u = blockIdx.x, b = blockIdx.y, h = blockIdx.z;
  const int tid = threadIdx.x;

  __shared__ float qs[kW][kD + 1];
  __shared__ float ks[kC][kD + 1];
  __shared__ float vs[kC][kD + 1];
  __shared__ float sins[kF][kD + 1];
  __shared__ float lg[kW][kC + 1];
  __shared__ float ss[kD];
  __shared__ int validc[kC];

  if (tid < kD) {
    float p = pds[tid];
    float sp = log1pf(expf(p));  // softplus
    ss[tid] = (1.0f / (sqrtf(192.0f) * logf(2.0f))) * sp;
  }
  if (tid < kC) {
    int p = u * kW + tid - 12;
    validc[tid] = (p >= 0 && p < kT && mask[b * kT + p] == 0) ? 1 : 0;
  }
  __syncthreads();

  for (int i = tid; i < kW * kD; i += 256) {
    int w = i / kD, d = i % kD;
    int t = u * kW + w;
    float v = 0.0f;
    if (t < kT) v = out[((size_t)(b * kT + t)) * kHID + h * kD + d] * ss[d];
    qs[w][d] = v;
  }
  for (int i = tid; i < kC * kD; i += 256) {
    int c = i / kD, d = i % kD;
    int p = u * kW + c - 12;
    float kval = 0.0f, vval = 0.0f;
    if (p >= 0 && p < kT) {
      size_t base = (size_t)(b * kT + p) * kKV;
      kval = (float)kv[base + h * kD + d];
      vval = (float)kv[base + kHID + h * kD + d];
    }
    ks[c][d] = kval;
    vs[c][d] = vval;
  }
  for (int i = tid; i < kF * kD; i += 256) {
    int f = i / kD, d = i % kD;
    sins[f][d] = sinb[f * kHID + h * kD + d];
  }
  __syncthreads();

  // logits (tanh soft-cap then mask)
  for (int i = tid; i < kW * kC; i += 256) {
    int w = i / kC, c = i % kC;
    float l = -3.4028234663852886e38f;
    int f = c - w;
    if (f >= 0 && f <= 12 && validc[c]) {
      float ac = 0.0f, bd = 0.0f;
      for (int d = 0; d < kD; d++) {
        float q = qs[w][d];
        ac += q * ks[c][d];
        bd += q * sins[f][d];
      }
      l = tanhf((ac + bd) * (1.0f / 50.0f)) * 50.0f;
    }
    lg[w][c] = l;
  }
  __syncthreads();

  // softmax per query row
  if (tid < kW) {
    float m = -3.4028234663852886e38f;
#pragma unroll
    for (int c = 0; c < kC; c++) m = fmaxf(m, lg[tid][c]);
    float e[kC];
    float s = 0.0f;
#pragma unroll
    for (int c = 0; c < kC; c++) {
      float ex = expf(lg[tid][c] - m);
      e[c] = ex;
      s += ex;
    }
    float inv = 1.0f / s;
#pragma unroll
    for (int c = 0; c < kC; c++) lg[tid][c] = e[c] * inv;
  }
  __syncthreads();

  // ctx = probs @ V (probs exactly 0 outside band [w, w+12])
  for (int i = tid; i < kW * kD; i += 256) {
    int w = i / kD, d = i % kD;
    int t = u * kW + w;
    if (t >= kT) continue;
    float acc = 0.0f;
#pragma unroll
    for (int c = 0; c < 13; c++) acc += lg[w][w + c] * vs[w + c][d];
    out[((size_t)(b * kT + t)) * kHID + h * kD + d] = acc;
  }
}

// ---------------------------------------------------------------------------
extern "C" void kernel_launch(void* const* d_in, const int* in_sizes, int n_in,
                              void* d_out, int out_size, void* d_ws, size_t ws_size,
                              hipStream_t stream) {
  if (ws_size < kWsNeed) return;  // beacon: absmax == 3.92 means ws too small

  const float* hs = (const float*)d_in[0];
  const unsigned char* mask = (const unsigned char*)d_in[1];
  const float* wq = (const float*)d_in[2];
  const float* wk = (const float*)d_in[3];
  const float* wv = (const float*)d_in[4];
  const float* wpos = (const float*)d_in[5];
  const float* pds = (const float*)d_in[6];
  float* out = (float*)d_out;

  char* ws = (char*)d_ws;
  bf16_t* kv = (bf16_t*)ws;
  bf16_t* wt = (bf16_t*)(ws + kWtOff);
  float* sinb = (float*)(ws + kSinOff);

  transpose_w<<<dim3(48, 48, 3), dim3(32, 8), 0, stream>>>(wq, wk, wv, wt);
  sinemb_kernel<<<dim3(6, 13), 256, 0, stream>>>(wpos, sinb);
  gemm_qkv<<<dim3(kNQKV / 128, kM / 128), 256, 0, stream>>>(hs, wt, out, kv);
  attn_kernel<<<dim3(kU, kB, kH), 256, 0, stream>>>(kv, mask, sinb, pds, out);
}